// Round 2
// baseline (1785.606 us; speedup 1.0000x reference)
//
#include <hip/hip_runtime.h>
#include <hip/hip_bf16.h>
#include <math.h>

typedef __hip_bfloat16 bf16;
typedef __attribute__((ext_vector_type(4))) float f32x4;
typedef __attribute__((ext_vector_type(8))) short s16x8;
typedef __attribute__((ext_vector_type(4))) short s16x4;

#define DEVI __device__ __forceinline__

constexpr int ZD = 8, HD = 96, WD = 180;
constexpr int WZ = 2, WH = 6, WWn = 12;
constexpr int MZ = 4, MH = 16, MW = 15;
constexpr int WP = 144, WN = 960;
constexpr int DIM = 384, HEADS = 12, DH = 32;
constexpr int TOK = ZD * HD * WD;            // 138240
constexpr size_t TOKDIM = (size_t)TOK * DIM; // 53084160
constexpr int NC = 8, CM = TOK / NC;         // 17280 rows per chunk

DEVI short f2b(float f) {
    bf16 h = __float2bfloat16(f);
    return *reinterpret_cast<short*>(&h);
}

// window-ordered row r -> spatial token index (fuses roll by SHIFT and window partition)
DEVI int row_to_token(int r) {
    int wn = r / WP;
    int p  = r - wn * WP;
    int mz = wn / (MH * MW);
    int rem = wn - mz * (MH * MW);
    int mh = rem / MW;
    int mw = rem - mh * MW;
    int lz = p / (WH * WWn);
    int rp = p - lz * (WH * WWn);
    int lh = rp / WWn;
    int lw = rp - lh * WWn;
    int zp = mz * WZ + lz + 1;  if (zp >= ZD) zp -= ZD;
    int hp = mh * WH + lh + 3;  if (hp >= HD) hp -= HD;
    int wp = mw * WWn + lw + 6; if (wp >= WD) wp -= WD;
    return (zp * HD + hp) * WD + wp;
}

// ---------------- prep kernels ----------------

__global__ __launch_bounds__(256)
void k_fill(float* __restrict__ out, int n, float v) {
    int i = blockIdx.x * blockDim.x + threadIdx.x;
    if (i < n) out[i] = v;
}

// wt[n*K + k] = bf16(w[k*N + n])   (transpose + cast)
__global__ __launch_bounds__(256)
void k_wcast(const float* __restrict__ w, bf16* __restrict__ wt, int K, int N) {
    int idx = blockIdx.x * blockDim.x + threadIdx.x;
    if (idx >= K * N) return;
    int n = idx / K;
    int k = idx - n * K;
    wt[idx] = __float2bfloat16(w[(size_t)k * N + n]);
}

// btr[(wt*12+h)*3312 + pos] = bt[pos*768 + wt*12 + h]
__global__ __launch_bounds__(256)
void k_btr(const float* __restrict__ bt, float* __restrict__ btr) {
    int idx = blockIdx.x * blockDim.x + threadIdx.x;
    if (idx >= 64 * 12 * 3312) return;
    int wth = idx / 3312;
    int pos = idx - wth * 3312;
    btr[idx] = bt[(size_t)pos * 768 + wth];
}

// gather x into window order + cast bf16
__global__ __launch_bounds__(256)
void k_gather_x(const float* __restrict__ x, bf16* __restrict__ xw) {
    int idx = blockIdx.x * blockDim.x + threadIdx.x;
    if (idx >= TOK * 96) return;
    int r  = idx / 96;
    int c4 = (idx - r * 96) * 4;
    int t  = row_to_token(r);
    const float4 vv = *(const float4*)(x + (size_t)t * DIM + c4);
    s16x4 o;
    o[0] = f2b(vv.x); o[1] = f2b(vv.y); o[2] = f2b(vv.z); o[3] = f2b(vv.w);
    *(s16x4*)((short*)xw + (size_t)r * DIM + c4) = o;
}

// ---------------- GEMM ----------------

DEVI void gload16(const bf16* g, bf16* l) {
    __builtin_amdgcn_global_load_lds(
        (const __attribute__((address_space(1))) void*)g,
        (__attribute__((address_space(3))) void*)l, 16, 0, 0);
}

// C = A(MxK, bf16 row-major) @ B (via BT: NxK bf16 row-major), epilogues:
// EPI 0: qkv scatter (scale q) -> out as q|k|v each (WN,HEADS,WP,DH) bf16
// EPI 1: +bias -> bf16 row-major
// EPI 2: +bias, exact GELU -> bf16 row-major
template <int EPI>
__global__ __launch_bounds__(256)
void k_gemm(const bf16* __restrict__ A, const bf16* __restrict__ BT,
            const float* __restrict__ bias, bf16* __restrict__ out,
            int M, int N, int K) {
    constexpr int BK = 64;
    __shared__ bf16 As[128 * BK];
    __shared__ bf16 Bs[128 * BK];

    const int nb = N >> 7;
    const int bm = blockIdx.x / nb;
    const int bn = blockIdx.x - bm * nb;
    const int tid = threadIdx.x;
    const int lane = tid & 63;
    const int wv = tid >> 6;
    const int wr = wv >> 1, wc = wv & 1;
    const int lg = lane >> 4, lc = lane & 15;

    const bf16* Ab = A + (size_t)bm * 128 * K;
    const bf16* Bb = BT + (size_t)bn * 128 * K;

    f32x4 acc[4][4];
#pragma unroll
    for (int mi = 0; mi < 4; mi++)
#pragma unroll
        for (int ni = 0; ni < 4; ni++) acc[mi][ni] = {0.f, 0.f, 0.f, 0.f};

    const int kiters = K / BK;
    const int srow = (lane >> 3);      // 0..7 within chunk
    const int scol = (lane & 7) * 8;   // 0..56

    for (int kt = 0; kt < kiters; kt++) {
        const int k0 = kt * BK;
#pragma unroll
        for (int i = 0; i < 4; i++) {
            int ch = wv * 4 + i;
            int row = ch * 8 + srow;
            gload16(Ab + (size_t)row * K + k0 + scol, &As[ch * 512]);
            gload16(Bb + (size_t)row * K + k0 + scol, &Bs[ch * 512]);
        }
        __syncthreads();
#pragma unroll
        for (int kk = 0; kk < 2; kk++) {
            s16x8 af[4], bfv[4];
#pragma unroll
            for (int mi = 0; mi < 4; mi++)
                af[mi] = *(const s16x8*)&As[(64 * wr + 16 * mi + lc) * BK + kk * 32 + 8 * lg];
#pragma unroll
            for (int ni = 0; ni < 4; ni++)
                bfv[ni] = *(const s16x8*)&Bs[(64 * wc + 16 * ni + lc) * BK + kk * 32 + 8 * lg];
#pragma unroll
            for (int mi = 0; mi < 4; mi++)
#pragma unroll
                for (int ni = 0; ni < 4; ni++)
                    acc[mi][ni] = __builtin_amdgcn_mfma_f32_16x16x32_bf16(
                        af[mi], bfv[ni], acc[mi][ni], 0, 0, 0);
        }
        __syncthreads();
    }

    const int rbase = bm * 128 + 64 * wr + 4 * lg;
    const int cbase = bn * 128 + 64 * wc + lc;
#pragma unroll
    for (int mi = 0; mi < 4; mi++) {
#pragma unroll
        for (int ni = 0; ni < 4; ni++) {
            const int gc = cbase + 16 * ni;
#pragma unroll
            for (int r2 = 0; r2 < 4; r2++) {
                const int gr = rbase + 16 * mi + r2;
                float val = acc[mi][ni][r2];
                if constexpr (EPI == 0) {
                    int which = gc / DIM;
                    int remc = gc - which * DIM;
                    int hh = remc >> 5, dh = remc & 31;
                    if (which == 0) val *= 0.17677669529663689f; // 1/sqrt(32)
                    int wn = gr / WP;
                    int p = gr - wn * WP;
                    out[(size_t)which * TOKDIM +
                        ((size_t)(wn * HEADS + hh) * WP + p) * DH + dh] = __float2bfloat16(val);
                } else if constexpr (EPI == 1) {
                    val += bias[gc];
                    out[(size_t)gr * N + gc] = __float2bfloat16(val);
                } else {
                    val += bias[gc];
                    val = 0.5f * val * (1.0f + erff(val * 0.70710678118654752f));
                    out[(size_t)gr * N + gc] = __float2bfloat16(val);
                }
            }
        }
    }
}

// ---------------- fused window attention ----------------
// block = one (window, head); 9 waves, wave s owns S rows [16s,16s+16)
__global__ __launch_bounds__(576)
void k_attn(const bf16* __restrict__ q, const bf16* __restrict__ kmat,
            const bf16* __restrict__ v, const float* __restrict__ btr,
            bf16* __restrict__ out) {
    __shared__ bf16 Qs[WP * DH];
    __shared__ bf16 Ks[WP * DH];
    __shared__ bf16 VTs[DH][160];
    __shared__ bf16 Ps[9][16][160];
    __shared__ int cA[WP];
    __shared__ int cB[WP];
    __shared__ unsigned char regn[WP];

    const int bid = blockIdx.x;
    const int wn = bid / HEADS, head = bid - wn * HEADS;
    const int mz = wn / (MH * MW);
    const int rem = wn - mz * (MH * MW);
    const int mh = rem / MW, mw = rem - (rem / MW) * MW;
    const int wt12h = (mz * MH + mh) * HEADS + head;

    const int tid = threadIdx.x;
    const int lane = tid & 63;
    const int wv = tid >> 6;
    const int lg = lane >> 4, lc = lane & 15;

    const size_t base = (size_t)(wn * HEADS + head) * (WP * DH);
    // stage Q, K (row-major [144][32]), V transposed [32][160] (zero-padded)
    {
        *(s16x8*)(Qs + tid * 8) = *(const s16x8*)(q + base + tid * 8);
        *(s16x8*)(Ks + tid * 8) = *(const s16x8*)(kmat + base + tid * 8);
        s16x8 vvv = *(const s16x8*)(v + base + tid * 8);
        int p = (tid * 8) >> 5;
        int d0 = (tid * 8) & 31;
        short* vt = (short*)VTs;
#pragma unroll
        for (int e = 0; e < 8; e++) vt[(d0 + e) * 160 + p] = vvv[e];
        if (tid < 512) { int d = tid >> 4; vt[d * 160 + 144 + (tid & 15)] = 0; }
        if (tid < WP) {
            int p2 = tid;
            int lz = p2 / 72, rp = p2 - lz * 72;
            int lh = rp / 12, lw = rp - lh * 12;
            int zp = mz * 2 + lz, hp = mh * 6 + lh, wp2 = mw * 12 + lw;
            int zr = (zp < 6) ? 0 : ((zp < 7) ? 1 : 2);
            int hr = (hp < 90) ? 0 : ((hp < 93) ? 1 : 2);
            int wr = (wp2 < 168) ? 0 : ((wp2 < 174) ? 1 : 2);
            regn[p2] = (unsigned char)(zr * 9 + hr * 3 + wr);
            cA[p2] = lz * 828 + lh * 23 + lw;
            cB[p2] = lz * 1656 + lh * 138 + (11 - lw);
        }
    }
    __syncthreads();

    const int s = wv;
    const f32x4 zf = {0.f, 0.f, 0.f, 0.f};
    f32x4 sacc[9];
    // QK^T : S[16 x 144]
    s16x8 aq = *(const s16x8*)(Qs + (16 * s + lc) * DH + 8 * lg);
#pragma unroll
    for (int jt = 0; jt < 9; jt++) {
        s16x8 bk = *(const s16x8*)(Ks + (16 * jt + lc) * DH + 8 * lg);
        sacc[jt] = __builtin_amdgcn_mfma_f32_16x16x32_bf16(aq, bk, zf, 0, 0, 0);
    }
    // bias + mask
    const int ib = 16 * s + 4 * lg;
    const float* btw = btr + (size_t)wt12h * 3312;
    int cAi[4]; int ri[4];
#pragma unroll
    for (int r2 = 0; r2 < 4; r2++) { cAi[r2] = cA[ib + r2]; ri[r2] = regn[ib + r2]; }
#pragma unroll
    for (int jt = 0; jt < 9; jt++) {
        int j = 16 * jt + lc;
        int cbj = cB[j];
        int rj = regn[j];
#pragma unroll
        for (int r2 = 0; r2 < 4; r2++) {
            float val = sacc[jt][r2] + btw[cAi[r2] + cbj];
            if (ri[r2] != rj) val -= 100.f;
            sacc[jt][r2] = val;
        }
    }
    // softmax per row (row lives in one 16-lane group x 9 regs)
#pragma unroll
    for (int r2 = 0; r2 < 4; r2++) {
        float m = sacc[0][r2];
#pragma unroll
        for (int jt = 1; jt < 9; jt++) m = fmaxf(m, sacc[jt][r2]);
#pragma unroll
        for (int o = 1; o < 16; o <<= 1) m = fmaxf(m, __shfl_xor(m, o));
        float sum = 0.f;
#pragma unroll
        for (int jt = 0; jt < 9; jt++) {
            float pe = __expf(sacc[jt][r2] - m);
            sacc[jt][r2] = pe;
            sum += pe;
        }
#pragma unroll
        for (int o = 1; o < 16; o <<= 1) sum += __shfl_xor(sum, o);
        float inv = 1.f / sum;
#pragma unroll
        for (int jt = 0; jt < 9; jt++) sacc[jt][r2] *= inv;
    }
    // P -> LDS (bf16, padded to 160 cols)
    {
        short* ps = (short*)&Ps[s][0][0];
#pragma unroll
        for (int jt = 0; jt < 9; jt++)
#pragma unroll
            for (int r2 = 0; r2 < 4; r2++)
                ps[(4 * lg + r2) * 160 + 16 * jt + lc] = f2b(sacc[jt][r2]);
#pragma unroll
        for (int r = lg; r < 16; r += 4) ps[r * 160 + 144 + lc] = 0;
    }
    __syncthreads();
    // PV : O[16 x 32]
    f32x4 oacc[2] = {zf, zf};
    const bf16* psb = &Ps[s][0][0];
#pragma unroll
    for (int c = 0; c < 5; c++) {
        s16x8 ap = *(const s16x8*)(psb + lc * 160 + 32 * c + 8 * lg);
#pragma unroll
        for (int nt = 0; nt < 2; nt++) {
            s16x8 bv = *(const s16x8*)(&VTs[0][0] + (16 * nt + lc) * 160 + 32 * c + 8 * lg);
            oacc[nt] = __builtin_amdgcn_mfma_f32_16x16x32_bf16(ap, bv, oacc[nt], 0, 0, 0);
        }
    }
    bf16* ob = out + (size_t)wn * (WP * DIM) + head * DH;
#pragma unroll
    for (int nt = 0; nt < 2; nt++)
#pragma unroll
        for (int r2 = 0; r2 < 4; r2++) {
            int i = ib + r2;
            ob[(size_t)i * DIM + 16 * nt + lc] = __float2bfloat16(oacc[nt][r2]);
        }
}

// ---------------- LayerNorm kernels ----------------

// x1[t] = x[t] + LN(y[r_local + r0]); scatter to token order; also bf16 copy
__global__ __launch_bounds__(128)
void k_ln1(const bf16* __restrict__ y, const float* __restrict__ x,
           const float* __restrict__ w, const float* __restrict__ b,
           float* __restrict__ x1, bf16* __restrict__ x1b, int r0) {
    __shared__ float red[4];
    const int rl = blockIdx.x, tid = threadIdx.x;
    const int t = row_to_token(r0 + rl);
    float v[3];
#pragma unroll
    for (int e = 0; e < 3; e++) v[e] = __bfloat162float(y[(size_t)rl * DIM + tid + 128 * e]);
    float s = v[0] + v[1] + v[2];
    float s2 = v[0] * v[0] + v[1] * v[1] + v[2] * v[2];
#pragma unroll
    for (int o = 1; o < 64; o <<= 1) { s += __shfl_xor(s, o); s2 += __shfl_xor(s2, o); }
    const int wv = tid >> 6;
    if ((tid & 63) == 0) { red[wv * 2] = s; red[wv * 2 + 1] = s2; }
    __syncthreads();
    s = red[0] + red[2]; s2 = red[1] + red[3];
    float mean = s * (1.f / 384.f);
    float var = fmaxf(s2 * (1.f / 384.f) - mean * mean, 0.f);
    float rs = rsqrtf(var + 1e-5f);
#pragma unroll
    for (int e = 0; e < 3; e++) {
        int c = tid + 128 * e;
        float o = (v[e] - mean) * rs * w[c] + b[c];
        float xo = x[(size_t)t * DIM + c] + o;
        x1[(size_t)t * DIM + c] = xo;
        ((short*)x1b)[(size_t)t * DIM + c] = f2b(xo);
    }
}

// out[r] = x1[r] + LN(h[r])
__global__ __launch_bounds__(128)
void k_ln2(const bf16* __restrict__ h, const float* __restrict__ x1,
           const float* __restrict__ w, const float* __restrict__ b,
           float* __restrict__ out) {
    __shared__ float red[4];
    const int r = blockIdx.x, tid = threadIdx.x;
    float v[3];
#pragma unroll
    for (int e = 0; e < 3; e++) v[e] = __bfloat162float(h[(size_t)r * DIM + tid + 128 * e]);
    float s = v[0] + v[1] + v[2];
    float s2 = v[0] * v[0] + v[1] * v[1] + v[2] * v[2];
#pragma unroll
    for (int o = 1; o < 64; o <<= 1) { s += __shfl_xor(s, o); s2 += __shfl_xor(s2, o); }
    const int wv = tid >> 6;
    if ((tid & 63) == 0) { red[wv * 2] = s; red[wv * 2 + 1] = s2; }
    __syncthreads();
    s = red[0] + red[2]; s2 = red[1] + red[3];
    float mean = s * (1.f / 384.f);
    float var = fmaxf(s2 * (1.f / 384.f) - mean * mean, 0.f);
    float rs = rsqrtf(var + 1e-5f);
#pragma unroll
    for (int e = 0; e < 3; e++) {
        int c = tid + 128 * e;
        float o = (v[e] - mean) * rs * w[c] + b[c];
        out[(size_t)r * DIM + c] = x1[(size_t)r * DIM + c] + o;
    }
}

// ---------------- launcher ----------------
// Workspace map (bytes):
//  W:   0          .. 13,713,408   weights bf16 (3,538,944) + btr f32 (10,174,464)
//  D1:  13,713,408 .. 332,218,368  qkv (318.5MB)  ->  x1 f32 (212.3MB) + x1b bf16 (106.2MB)
//  D2:  332,218,368.. 438,386,688  xw -> aout -> htmp (106.2MB)
//  D3:  438,386,688.. 491,470,848  ytmp chunk / h1 chunk (53.1MB)
// peak: 491,470,848 B (~469 MiB)

extern "C" void kernel_launch(void* const* d_in, const int* in_sizes, int n_in,
                              void* d_out, int out_size, void* d_ws, size_t ws_size,
                              hipStream_t stream) {
    const float* x      = (const float*)d_in[0];
    const float* w_qkv  = (const float*)d_in[1];
    const float* w_proj = (const float*)d_in[2];
    const float* b_proj = (const float*)d_in[3];
    const float* btab   = (const float*)d_in[4];
    const float* ln1w   = (const float*)d_in[5];
    const float* ln1b   = (const float*)d_in[6];
    const float* ln2w   = (const float*)d_in[7];
    const float* ln2b   = (const float*)d_in[8];
    const float* w1     = (const float*)d_in[9];
    const float* b1     = (const float*)d_in[10];
    const float* w2     = (const float*)d_in[11];
    const float* b2     = (const float*)d_in[12];

    const size_t NEED = 491470848ULL;
    if (ws_size < NEED) {
        // diagnostic: signal "workspace too small" via absmax ~= 12345
        k_fill<<<(out_size + 255) / 256, 256, 0, stream>>>((float*)d_out, out_size, 12345.0f);
        return;
    }

    char* ws = (char*)d_ws;
    bf16* wqkvT  = (bf16*)(ws + 0);
    bf16* wprojT = (bf16*)(ws + 884736);
    bf16* w1T    = (bf16*)(ws + 1179648);
    bf16* w2T    = (bf16*)(ws + 2359296);
    float* btr   = (float*)(ws + 3538944);

    const size_t D1 = 13713408;
    const size_t D2 = 332218368;
    const size_t D3 = 438386688;

    bf16* qkv  = (bf16*)(ws + D1);
    float* x1  = (float*)(ws + D1);
    bf16* x1b  = (bf16*)(ws + D1 + 212336640);
    bf16* xw   = (bf16*)(ws + D2);
    bf16* aout = (bf16*)(ws + D2);
    bf16* htmp = (bf16*)(ws + D2);
    bf16* ytmp = (bf16*)(ws + D3);
    bf16* h1c  = (bf16*)(ws + D3);

    // prep
    k_wcast<<<(442368 + 255) / 256, 256, 0, stream>>>(w_qkv, wqkvT, 384, 1152);
    k_wcast<<<(147456 + 255) / 256, 256, 0, stream>>>(w_proj, wprojT, 384, 384);
    k_wcast<<<(589824 + 255) / 256, 256, 0, stream>>>(w1, w1T, 384, 1536);
    k_wcast<<<(589824 + 255) / 256, 256, 0, stream>>>(w2, w2T, 1536, 384);
    k_btr<<<(2543616 + 255) / 256, 256, 0, stream>>>(btab, btr);
    k_gather_x<<<(TOK * 96 + 255) / 256, 256, 0, stream>>>(x, xw);

    // qkv = xw @ w_qkv  (scatter epilogue)
    k_gemm<0><<<dim3((TOK / 128) * 9), 256, 0, stream>>>(xw, wqkvT, nullptr, qkv, TOK, 1152, 384);

    // attention
    k_attn<<<dim3(WN * HEADS), 576, 0, stream>>>(qkv, qkv + TOKDIM, qkv + 2 * TOKDIM, btr, aout);

    // proj + LN1 + residual, chunked over window-order rows (qkv region becomes x1/x1b)
    for (int c = 0; c < NC; c++) {
        k_gemm<1><<<dim3((CM / 128) * 3), 256, 0, stream>>>(
            aout + (size_t)c * CM * DIM, wprojT, b_proj, ytmp, CM, 384, 384);
        k_ln1<<<dim3(CM), 128, 0, stream>>>(ytmp, x, ln1w, ln1b, x1, x1b, c * CM);
    }

    // MLP, chunked over token-order rows
    for (int c = 0; c < NC; c++) {
        k_gemm<2><<<dim3((CM / 128) * 12), 256, 0, stream>>>(
            x1b + (size_t)c * CM * DIM, w1T, b1, h1c, CM, 1536, 384);
        k_gemm<1><<<dim3((CM / 128) * 3), 256, 0, stream>>>(
            h1c, w2T, b2, htmp + (size_t)c * CM * DIM, CM, 384, 1536);
    }

    // final LN + residual -> d_out (fp32)
    k_ln2<<<dim3(TOK), 128, 0, stream>>>(htmp, x1, ln2w, ln2b, (float*)d_out);
}

// Round 7
// 1689.696 us; speedup vs baseline: 1.0568x; 1.0568x over previous
//
#include <hip/hip_runtime.h>
#include <hip/hip_bf16.h>
#include <math.h>

typedef __hip_bfloat16 bf16;
typedef __attribute__((ext_vector_type(4))) float f32x4;
typedef __attribute__((ext_vector_type(8))) short s16x8;
typedef __attribute__((ext_vector_type(4))) short s16x4;

#define DEVI __device__ __forceinline__

constexpr int ZD = 8, HD = 96, WD = 180;
constexpr int WZ = 2, WH = 6, WWn = 12;
constexpr int MZ = 4, MH = 16, MW = 15;
constexpr int WP = 144, WN = 960;
constexpr int DIM = 384, HEADS = 12, DH = 32;
constexpr int TOK = ZD * HD * WD;            // 138240
constexpr size_t TOKDIM = (size_t)TOK * DIM; // 53084160
constexpr int NC = 9, CM = TOK / NC;         // 15360 rows/chunk, mb=120 (div 8)

DEVI short f2b(float f) {
    bf16 h = __float2bfloat16(f);
    return *reinterpret_cast<short*>(&h);
}

DEVI int row_to_token(int r) {
    int wn = r / WP;
    int p  = r - wn * WP;
    int mz = wn / (MH * MW);
    int rem = wn - mz * (MH * MW);
    int mh = rem / MW;
    int mw = rem - mh * MW;
    int lz = p / (WH * WWn);
    int rp = p - lz * (WH * WWn);
    int lh = rp / WWn;
    int lw = rp - lh * WWn;
    int zp = mz * WZ + lz + 1;  if (zp >= ZD) zp -= ZD;
    int hp = mh * WH + lh + 3;  if (hp >= HD) hp -= HD;
    int wp = mw * WWn + lw + 6; if (wp >= WD) wp -= WD;
    return (zp * HD + hp) * WD + wp;
}

// ---------------- prep kernels ----------------

__global__ __launch_bounds__(256)
void k_fill(float* __restrict__ out, int n, float v) {
    int i = blockIdx.x * blockDim.x + threadIdx.x;
    if (i < n) out[i] = v;
}

__global__ __launch_bounds__(256)
void k_wcast(const float* __restrict__ w, bf16* __restrict__ wt, int K, int N) {
    int idx = blockIdx.x * blockDim.x + threadIdx.x;
    if (idx >= K * N) return;
    int n = idx / K;
    int k = idx - n * K;
    wt[idx] = __float2bfloat16(w[(size_t)k * N + n]);
}

// btr[(wt*12+h)*3312 + pos] = bt[pos*768 + wt*12 + h] * log2(e)
__global__ __launch_bounds__(256)
void k_btr(const float* __restrict__ bt, float* __restrict__ btr) {
    int idx = blockIdx.x * blockDim.x + threadIdx.x;
    if (idx >= 64 * 12 * 3312) return;
    int wth = idx / 3312;
    int pos = idx - wth * 3312;
    btr[idx] = bt[(size_t)pos * 768 + wth] * 1.4426950408889634f;
}

// expand bias + (z,h)-region mask -> tab[(wt*12+h)][i][j], bf16, log2-scaled
__global__ __launch_bounds__(256)
void k_mktab(const float* __restrict__ btr, bf16* __restrict__ tab) {
    int idx = blockIdx.x * blockDim.x + threadIdx.x;
    if (idx >= 768 * WP * WP) return;
    int t = idx / (WP * WP);
    int e = idx - t * (WP * WP);
    int i = e / WP, j = e - i * WP;
    int wt = t / 12;
    int mz = wt >> 4, mh = wt & 15;
    int lzi = i / 72, ri_ = i - lzi * 72, lhi = ri_ / 12, lwi = ri_ - lhi * 12;
    int lzj = j / 72, rj_ = j - lzj * 72, lhj = rj_ / 12, lwj = rj_ - lhj * 12;
    int cA = lzi * 828 + lhi * 23 + lwi;
    int cB = lzj * 1656 + lhj * 138 + (11 - lwj);
    float vv = btr[(size_t)t * 3312 + cA + cB];
    int zri = (mz == 3) ? (lzi + 1) : 0, zrj = (mz == 3) ? (lzj + 1) : 0;
    int hri = (mh == 15) ? (lhi < 3 ? 1 : 2) : 0, hrj = (mh == 15) ? (lhj < 3 ? 1 : 2) : 0;
    if (zri != zrj || hri != hrj) vv -= 144.26950408889634f; // -100*log2(e)
    tab[idx] = __float2bfloat16(vv);
}

__global__ __launch_bounds__(256)
void k_gather_x(const float* __restrict__ x, bf16* __restrict__ xw) {
    int idx = blockIdx.x * blockDim.x + threadIdx.x;
    if (idx >= TOK * 96) return;
    int r  = idx / 96;
    int c4 = (idx - r * 96) * 4;
    int t  = row_to_token(r);
    const float4 vv = *(const float4*)(x + (size_t)t * DIM + c4);
    s16x4 o;
    o[0] = f2b(vv.x); o[1] = f2b(vv.y); o[2] = f2b(vv.z); o[3] = f2b(vv.w);
    *(s16x4*)((short*)xw + (size_t)r * DIM + c4) = o;
}

// ---------------- GEMM ----------------

DEVI void gload16(const bf16* g, bf16* l) {
    __builtin_amdgcn_global_load_lds(
        (const __attribute__((address_space(1))) void*)g,
        (__attribute__((address_space(3))) void*)l, 16, 0, 0);
}

// C = A(MxK) @ BT(NxK)^T ; XCD-grouped block swizzle (requires (M/128)%8==0).
// EPI 0: qkv scatter (q scaled by 1/sqrt(32)*log2e); EPI 1: +bias; EPI 2: +bias,GELU
template <int EPI>
__global__ __launch_bounds__(256)
void k_gemm(const bf16* __restrict__ A, const bf16* __restrict__ BT,
            const float* __restrict__ bias, bf16* __restrict__ out,
            int M, int N, int K) {
    constexpr int BK = 64;
    __shared__ bf16 As[128 * BK];
    __shared__ bf16 Bs[128 * BK];

    const int nb = N >> 7;
    // swizzle: all bn-blocks of one bm land on the same XCD (bm == bid%8 mod 8)
    const int g = blockIdx.x;
    const int xcd = g & 7;
    const int ii = g >> 3;
    const int tt = ii / nb;
    const int bm = tt * 8 + xcd;
    const int bn = ii - tt * nb;

    const int tid = threadIdx.x;
    const int lane = tid & 63;
    const int wv = tid >> 6;
    const int wr = wv >> 1, wc = wv & 1;
    const int lg = lane >> 4, lc = lane & 15;

    const bf16* Ab = A + (size_t)bm * 128 * K;
    const bf16* Bb = BT + (size_t)bn * 128 * K;

    f32x4 acc[4][4];
#pragma unroll
    for (int mi = 0; mi < 4; mi++)
#pragma unroll
        for (int ni = 0; ni < 4; ni++) acc[mi][ni] = {0.f, 0.f, 0.f, 0.f};

    const int kiters = K / BK;
    const int srow = (lane >> 3);
    const int scol = (lane & 7) * 8;

    for (int kt = 0; kt < kiters; kt++) {
        const int k0 = kt * BK;
#pragma unroll
        for (int i = 0; i < 4; i++) {
            int ch = wv * 4 + i;
            int row = ch * 8 + srow;
            gload16(Ab + (size_t)row * K + k0 + scol, &As[ch * 512]);
            gload16(Bb + (size_t)row * K + k0 + scol, &Bs[ch * 512]);
        }
        // explicit drain of global_load_lds before the barrier: do NOT rely on
        // the compiler's implicit vmcnt(0)-before-s_barrier (replay-race suspect)
        asm volatile("s_waitcnt vmcnt(0)" ::: "memory");
        __syncthreads();
#pragma unroll
        for (int kk = 0; kk < 2; kk++) {
            s16x8 af[4], bfv[4];
#pragma unroll
            for (int mi = 0; mi < 4; mi++)
                af[mi] = *(const s16x8*)&As[(64 * wr + 16 * mi + lc) * BK + kk * 32 + 8 * lg];
#pragma unroll
            for (int ni = 0; ni < 4; ni++)
                bfv[ni] = *(const s16x8*)&Bs[(64 * wc + 16 * ni + lc) * BK + kk * 32 + 8 * lg];
#pragma unroll
            for (int mi = 0; mi < 4; mi++)
#pragma unroll
                for (int ni = 0; ni < 4; ni++)
                    acc[mi][ni] = __builtin_amdgcn_mfma_f32_16x16x32_bf16(
                        af[mi], bfv[ni], acc[mi][ni], 0, 0, 0);
        }
        __syncthreads();
    }

    const int rbase = bm * 128 + 64 * wr + 4 * lg;
    const int cbase = bn * 128 + 64 * wc + lc;
#pragma unroll
    for (int mi = 0; mi < 4; mi++) {
#pragma unroll
        for (int ni = 0; ni < 4; ni++) {
            const int gc = cbase + 16 * ni;
#pragma unroll
            for (int r2 = 0; r2 < 4; r2++) {
                const int gr = rbase + 16 * mi + r2;
                float val = acc[mi][ni][r2];
                if constexpr (EPI == 0) {
                    int which = gc / DIM;
                    int remc = gc - which * DIM;
                    int hh = remc >> 5, dh = remc & 31;
                    if (which == 0) val *= 0.25503527f; // (1/sqrt(32))*log2(e)
                    int wn = gr / WP;
                    int p = gr - wn * WP;
                    out[(size_t)which * TOKDIM +
                        ((size_t)(wn * HEADS + hh) * WP + p) * DH + dh] = __float2bfloat16(val);
                } else if constexpr (EPI == 1) {
                    val += bias[gc];
                    out[(size_t)gr * N + gc] = __float2bfloat16(val);
                } else {
                    val += bias[gc];
                    val = 0.5f * val * (1.0f + erff(val * 0.70710678118654752f));
                    out[(size_t)gr * N + gc] = __float2bfloat16(val);
                }
            }
        }
    }
}

// ---------------- fused window attention ----------------
// block = one (window, head), LINEAR bid mapping (replay-proven dispatch order);
// 9 waves x 16-row strips. Row-major Ps + b128 reads (round-1-proven).
// Softmax in exp2 domain, no max-subtract, normalize O after PV.
__global__ __launch_bounds__(576)
void k_attn(const bf16* __restrict__ q, const bf16* __restrict__ kmat,
            const bf16* __restrict__ v, const bf16* __restrict__ tab,
            bf16* __restrict__ out) {
    __shared__ bf16 Qs[WP * DH];        // [144][32]
    __shared__ bf16 Ks[WP * DH];
    __shared__ bf16 VTs[DH * 160];      // [32][160], cols 144..159 zero
    __shared__ bf16 Ps[9][16][160];     // per-wave [16 rows][160 cols] P (unnormalized)
    __shared__ unsigned char regn[WP];

    const int bid = blockIdx.x;
    const int wn = bid / HEADS, head = bid - wn * HEADS;
    const int mz = wn / (MH * MW);
    const int rem = wn - mz * (MH * MW);
    const int mh = rem / MW, mw = rem - (rem / MW) * MW;
    const int tile = (mz * MH + mh) * HEADS + head;   // wt*12 + head

    const int tid = threadIdx.x;
    const int lane = tid & 63;
    const int s = tid >> 6;
    const int lg = lane >> 4, lc = lane & 15;

    const size_t base = (size_t)(wn * HEADS + head) * (WP * DH);
    {
        *(s16x8*)(Qs + tid * 8) = *(const s16x8*)(q + base + tid * 8);
        *(s16x8*)(Ks + tid * 8) = *(const s16x8*)(kmat + base + tid * 8);
        s16x8 vv = *(const s16x8*)(v + base + tid * 8);
        int p = tid >> 2;
        int d0 = (tid & 3) * 8;
        short* vt = (short*)VTs;
#pragma unroll
        for (int e = 0; e < 8; e++) vt[(d0 + e) * 160 + p] = vv[e];
        if (tid < 512) { int d = tid >> 4; vt[d * 160 + 144 + (tid & 15)] = 0; }
        if (tid < WP) {
            int lz = tid / 72, rp = tid - lz * 72;
            int lh = rp / 12, lw = rp - lh * 12;
            int zr = (mz == 3) ? (lz + 1) : 0;
            int hr = (mh == 15) ? (lh < 3 ? 1 : 2) : 0;
            int wbit = (lw < 6) ? 1 : 2;
            regn[tid] = (unsigned char)((zr * 3 + hr) * 4 + wbit);
        }
    }
    __syncthreads();

    const f32x4 zf = {0.f, 0.f, 0.f, 0.f};
    f32x4 sacc[9];
    // QK^T (q pre-scaled incl log2e)
    s16x8 aq = *(const s16x8*)(Qs + (16 * s + lc) * DH + 8 * lg);
#pragma unroll
    for (int jt = 0; jt < 9; jt++) {
        s16x8 bk = *(const s16x8*)(Ks + (16 * jt + lc) * DH + 8 * lg);
        sacc[jt] = __builtin_amdgcn_mfma_f32_16x16x32_bf16(aq, bk, zf, 0, 0, 0);
    }
    // + expanded bias (includes z/h mask), log2-scaled
    const int ib = 16 * s + 4 * lg;
    const bf16* tb = tab + (size_t)tile * (WP * WP);
#pragma unroll
    for (int jt = 0; jt < 9; jt++) {
        int j = 16 * jt + lc;
#pragma unroll
        for (int r2 = 0; r2 < 4; r2++)
            sacc[jt][r2] += __bfloat162float(tb[(ib + r2) * WP + j]);
    }
    // residual w-region mask (only boundary-mw windows)
    if (mw == 14) {
        int ri[4];
#pragma unroll
        for (int r2 = 0; r2 < 4; r2++) ri[r2] = regn[ib + r2];
#pragma unroll
        for (int jt = 0; jt < 9; jt++) {
            int rj = regn[16 * jt + lc];
#pragma unroll
            for (int r2 = 0; r2 < 4; r2++) {
                bool m = ((ri[r2] >> 2) == (rj >> 2)) && ((ri[r2] & 3) != (rj & 3));
                if (m) sacc[jt][r2] -= 144.2695f;
            }
        }
    }
    // exp2 (no max-subtract; logits tiny, masked -> exp2(-144) = 0) + row sums
    float inv[4];
#pragma unroll
    for (int r2 = 0; r2 < 4; r2++) {
        float sum = 0.f;
#pragma unroll
        for (int jt = 0; jt < 9; jt++) {
            float pe = exp2f(sacc[jt][r2]);
            sacc[jt][r2] = pe;
            sum += pe;
        }
#pragma unroll
        for (int o = 1; o < 16; o <<= 1) sum += __shfl_xor(sum, o);
        inv[r2] = 1.0f / sum;
    }
    // store unnormalized P row-major [16][160]
    {
        short* ps = (short*)&Ps[s][0][0];
#pragma unroll
        for (int jt = 0; jt < 9; jt++)
#pragma unroll
            for (int r2 = 0; r2 < 4; r2++)
                ps[(4 * lg + r2) * 160 + 16 * jt + lc] = f2b(sacc[jt][r2]);
#pragma unroll
        for (int r = lg; r < 16; r += 4) ps[r * 160 + 144 + lc] = 0;
    }
    __syncthreads();
    // PV : O[16 x 32] (b128 fragment reads)
    f32x4 oacc[2] = {zf, zf};
    const bf16* psb = &Ps[s][0][0];
#pragma unroll
    for (int c = 0; c < 5; c++) {
        s16x8 ap = *(const s16x8*)(psb + lc * 160 + 32 * c + 8 * lg);
#pragma unroll
        for (int nt = 0; nt < 2; nt++) {
            s16x8 bv = *(const s16x8*)(VTs + (16 * nt + lc) * 160 + 32 * c + 8 * lg);
            oacc[nt] = __builtin_amdgcn_mfma_f32_16x16x32_bf16(ap, bv, oacc[nt], 0, 0, 0);
        }
    }
    bf16* ob = out + (size_t)wn * (WP * DIM) + head * DH;
#pragma unroll
    for (int nt = 0; nt < 2; nt++)
#pragma unroll
        for (int r2 = 0; r2 < 4; r2++)
            ob[(size_t)(ib + r2) * DIM + 16 * nt + lc] =
                __float2bfloat16(oacc[nt][r2] * inv[r2]);
}

// ---------------- LayerNorm kernels ----------------

__global__ __launch_bounds__(128)
void k_ln1(const bf16* __restrict__ y, const float* __restrict__ x,
           const float* __restrict__ w, const float* __restrict__ b,
           bf16* __restrict__ x1b, int r0) {
    __shared__ float red[4];
    const int rl = blockIdx.x, tid = threadIdx.x;
    const int t = row_to_token(r0 + rl);
    float v[3];
#pragma unroll
    for (int e = 0; e < 3; e++) v[e] = __bfloat162float(y[(size_t)rl * DIM + tid + 128 * e]);
    float s = v[0] + v[1] + v[2];
    float s2 = v[0] * v[0] + v[1] * v[1] + v[2] * v[2];
#pragma unroll
    for (int o = 1; o < 64; o <<= 1) { s += __shfl_xor(s, o); s2 += __shfl_xor(s2, o); }
    const int wv = tid >> 6;
    if ((tid & 63) == 0) { red[wv * 2] = s; red[wv * 2 + 1] = s2; }
    __syncthreads();
    s = red[0] + red[2]; s2 = red[1] + red[3];
    float mean = s * (1.f / 384.f);
    float var = fmaxf(s2 * (1.f / 384.f) - mean * mean, 0.f);
    float rs = rsqrtf(var + 1e-5f);
#pragma unroll
    for (int e = 0; e < 3; e++) {
        int c = tid + 128 * e;
        float o = (v[e] - mean) * rs * w[c] + b[c];
        float xo = x[(size_t)t * DIM + c] + o;
        ((short*)x1b)[(size_t)t * DIM + c] = f2b(xo);
    }
}

__global__ __launch_bounds__(128)
void k_ln2(const bf16* __restrict__ h, const bf16* __restrict__ x1b,
           const float* __restrict__ w, const float* __restrict__ b,
           float* __restrict__ out) {
    __shared__ float red[4];
    const int r = blockIdx.x, tid = threadIdx.x;
    float v[3];
#pragma unroll
    for (int e = 0; e < 3; e++) v[e] = __bfloat162float(h[(size_t)r * DIM + tid + 128 * e]);
    float s = v[0] + v[1] + v[2];
    float s2 = v[0] * v[0] + v[1] * v[1] + v[2] * v[2];
#pragma unroll
    for (int o = 1; o < 64; o <<= 1) { s += __shfl_xor(s, o); s2 += __shfl_xor(s2, o); }
    const int wv = tid >> 6;
    if ((tid & 63) == 0) { red[wv * 2] = s; red[wv * 2 + 1] = s2; }
    __syncthreads();
    s = red[0] + red[2]; s2 = red[1] + red[3];
    float mean = s * (1.f / 384.f);
    float var = fmaxf(s2 * (1.f / 384.f) - mean * mean, 0.f);
    float rs = rsqrtf(var + 1e-5f);
#pragma unroll
    for (int e = 0; e < 3; e++) {
        int c = tid + 128 * e;
        float o = (v[e] - mean) * rs * w[c] + b[c];
        out[(size_t)r * DIM + c] = __bfloat162float(x1b[(size_t)r * DIM + c]) + o;
    }
}

// ---------------- launcher ----------------
// Workspace map (bytes):
//  0         wqkvT(884736) wprojT(294912) w1T(1179648) w2T(1179648)
//  3538944   btr f32 (10174464)
//  13713408  tab bf16 (31850496)
//  45563904  D1: qkv (318504960) -> x1b(106168320) + ytmp/h1c(@D1+106168320)
//  364068864 D2: xw -> aout -> htmp (106168320)
//  peak 470237184 (< 491470848 proven available in round 2)

extern "C" void kernel_launch(void* const* d_in, const int* in_sizes, int n_in,
                              void* d_out, int out_size, void* d_ws, size_t ws_size,
                              hipStream_t stream) {
    const float* x      = (const float*)d_in[0];
    const float* w_qkv  = (const float*)d_in[1];
    const float* w_proj = (const float*)d_in[2];
    const float* b_proj = (const float*)d_in[3];
    const float* btab   = (const float*)d_in[4];
    const float* ln1w   = (const float*)d_in[5];
    const float* ln1b   = (const float*)d_in[6];
    const float* ln2w   = (const float*)d_in[7];
    const float* ln2b   = (const float*)d_in[8];
    const float* w1     = (const float*)d_in[9];
    const float* b1     = (const float*)d_in[10];
    const float* w2     = (const float*)d_in[11];
    const float* b2     = (const float*)d_in[12];

    const size_t NEED = 470237184ULL;
    if (ws_size < NEED) {
        k_fill<<<(out_size + 255) / 256, 256, 0, stream>>>((float*)d_out, out_size, 12345.0f);
        return;
    }

    char* ws = (char*)d_ws;
    bf16* wqkvT  = (bf16*)(ws + 0);
    bf16* wprojT = (bf16*)(ws + 884736);
    bf16* w1T    = (bf16*)(ws + 1179648);
    bf16* w2T    = (bf16*)(ws + 2359296);
    float* btr   = (float*)(ws + 3538944);
    bf16* tab    = (bf16*)(ws + 13713408);

    const size_t D1 = 45563904;
    const size_t D2 = 364068864;

    bf16* qkv  = (bf16*)(ws + D1);
    bf16* x1b  = (bf16*)(ws + D1);
    bf16* ytmp = (bf16*)(ws + D1 + 106168320);
    bf16* h1c  = (bf16*)(ws + D1 + 106168320);
    bf16* xw   = (bf16*)(ws + D2);
    bf16* aout = (bf16*)(ws + D2);
    bf16* htmp = (bf16*)(ws + D2);

    // prep
    k_wcast<<<(442368 + 255) / 256, 256, 0, stream>>>(w_qkv, wqkvT, 384, 1152);
    k_wcast<<<(147456 + 255) / 256, 256, 0, stream>>>(w_proj, wprojT, 384, 384);
    k_wcast<<<(589824 + 255) / 256, 256, 0, stream>>>(w1, w1T, 384, 1536);
    k_wcast<<<(589824 + 255) / 256, 256, 0, stream>>>(w2, w2T, 1536, 384);
    k_btr<<<(2543616 + 255) / 256, 256, 0, stream>>>(btab, btr);
    k_mktab<<<(768 * WP * WP + 255) / 256, 256, 0, stream>>>(btr, tab);
    k_gather_x<<<(TOK * 96 + 255) / 256, 256, 0, stream>>>(x, xw);

    // qkv = xw @ w_qkv (scatter epilogue)
    k_gemm<0><<<dim3((TOK / 128) * 9), 256, 0, stream>>>(xw, wqkvT, nullptr, qkv, TOK, 1152, 384);

    // attention
    k_attn<<<dim3(WN * HEADS), 576, 0, stream>>>(qkv, qkv + TOKDIM, qkv + 2 * TOKDIM, tab, aout);

    // proj + LN1 + residual (chunked; qkv region becomes x1b)
    for (int c = 0; c < NC; c++) {
        k_gemm<1><<<dim3((CM / 128) * 3), 256, 0, stream>>>(
            aout + (size_t)c * CM * DIM, wprojT, b_proj, ytmp, CM, 384, 384);
        k_ln1<<<dim3(CM), 128, 0, stream>>>(ytmp, x, ln1w, ln1b, x1b, c * CM);
    }

    // MLP (chunked)
    for (int c = 0; c < NC; c++) {
        k_gemm<2><<<dim3((CM / 128) * 12), 256, 0, stream>>>(
            x1b + (size_t)c * CM * DIM, w1T, b1, h1c, CM, 1536, 384);
        k_gemm<1><<<dim3((CM / 128) * 3), 256, 0, stream>>>(
            h1c, w2T, b2, htmp + (size_t)c * CM * DIM, CM, 384, 1536);
    }

    // final LN + residual -> d_out (fp32)
    k_ln2<<<dim3(TOK), 128, 0, stream>>>(htmp, x1b, ln2w, ln2b, (float*)d_out);
}

// Round 8
// 1440.528 us; speedup vs baseline: 1.2395x; 1.1730x over previous
//
#include <hip/hip_runtime.h>
#include <hip/hip_bf16.h>
#include <math.h>

typedef __hip_bfloat16 bf16;
typedef __attribute__((ext_vector_type(4))) float f32x4;
typedef __attribute__((ext_vector_type(8))) short s16x8;
typedef __attribute__((ext_vector_type(4))) short s16x4;

#define DEVI __device__ __forceinline__

constexpr int ZD = 8, HD = 96, WD = 180;
constexpr int WZ = 2, WH = 6, WWn = 12;
constexpr int MZ = 4, MH = 16, MW = 15;
constexpr int WP = 144, WN = 960;
constexpr int DIM = 384, HEADS = 12, DH = 32;
constexpr int TOK = ZD * HD * WD;            // 138240
constexpr size_t TOKDIM = (size_t)TOK * DIM; // 53084160
constexpr int NC = 3, CM = TOK / NC;         // 46080 rows/chunk, mb=360 (div 8)

DEVI short f2b(float f) {
    bf16 h = __float2bfloat16(f);
    return *reinterpret_cast<short*>(&h);
}

DEVI int row_to_token(int r) {
    int wn = r / WP;
    int p  = r - wn * WP;
    int mz = wn / (MH * MW);
    int rem = wn - mz * (MH * MW);
    int mh = rem / MW;
    int mw = rem - mh * MW;
    int lz = p / (WH * WWn);
    int rp = p - lz * (WH * WWn);
    int lh = rp / WWn;
    int lw = rp - lh * WWn;
    int zp = mz * WZ + lz + 1;  if (zp >= ZD) zp -= ZD;
    int hp = mh * WH + lh + 3;  if (hp >= HD) hp -= HD;
    int wp = mw * WWn + lw + 6; if (wp >= WD) wp -= WD;
    return (zp * HD + hp) * WD + wp;
}

// ---------------- prep kernels ----------------

__global__ __launch_bounds__(256)
void k_fill(float* __restrict__ out, int n, float v) {
    int i = blockIdx.x * blockDim.x + threadIdx.x;
    if (i < n) out[i] = v;
}

__global__ __launch_bounds__(256)
void k_wcast(const float* __restrict__ w, bf16* __restrict__ wt, int K, int N) {
    int idx = blockIdx.x * blockDim.x + threadIdx.x;
    if (idx >= K * N) return;
    int n = idx / K;
    int k = idx - n * K;
    wt[idx] = __float2bfloat16(w[(size_t)k * N + n]);
}

// btr[(wt*12+h)*3312 + pos] = bt[pos*768 + wt*12 + h] * log2(e)
__global__ __launch_bounds__(256)
void k_btr(const float* __restrict__ bt, float* __restrict__ btr) {
    int idx = blockIdx.x * blockDim.x + threadIdx.x;
    if (idx >= 64 * 12 * 3312) return;
    int wth = idx / 3312;
    int pos = idx - wth * 3312;
    btr[idx] = bt[(size_t)pos * 768 + wth] * 1.4426950408889634f;
}

// expand bias + (z,h)-region mask -> tab[(wt*12+h)][i][j], bf16, log2-scaled
__global__ __launch_bounds__(256)
void k_mktab(const float* __restrict__ btr, bf16* __restrict__ tab) {
    int idx = blockIdx.x * blockDim.x + threadIdx.x;
    if (idx >= 768 * WP * WP) return;
    int t = idx / (WP * WP);
    int e = idx - t * (WP * WP);
    int i = e / WP, j = e - i * WP;
    int wt = t / 12;
    int mz = wt >> 4, mh = wt & 15;
    int lzi = i / 72, ri_ = i - lzi * 72, lhi = ri_ / 12, lwi = ri_ - lhi * 12;
    int lzj = j / 72, rj_ = j - lzj * 72, lhj = rj_ / 12, lwj = rj_ - lhj * 12;
    int cA = lzi * 828 + lhi * 23 + lwi;
    int cB = lzj * 1656 + lhj * 138 + (11 - lwj);
    float vv = btr[(size_t)t * 3312 + cA + cB];
    int zri = (mz == 3) ? (lzi + 1) : 0, zrj = (mz == 3) ? (lzj + 1) : 0;
    int hri = (mh == 15) ? (lhi < 3 ? 1 : 2) : 0, hrj = (mh == 15) ? (lhj < 3 ? 1 : 2) : 0;
    if (zri != zrj || hri != hrj) vv -= 144.26950408889634f; // -100*log2(e)
    tab[idx] = __float2bfloat16(vv);
}

__global__ __launch_bounds__(256)
void k_gather_x(const float* __restrict__ x, bf16* __restrict__ xw) {
    int idx = blockIdx.x * blockDim.x + threadIdx.x;
    if (idx >= TOK * 96) return;
    int r  = idx / 96;
    int c4 = (idx - r * 96) * 4;
    int t  = row_to_token(r);
    const float4 vv = *(const float4*)(x + (size_t)t * DIM + c4);
    s16x4 o;
    o[0] = f2b(vv.x); o[1] = f2b(vv.y); o[2] = f2b(vv.z); o[3] = f2b(vv.w);
    *(s16x4*)((short*)xw + (size_t)r * DIM + c4) = o;
}

// ---------------- GEMM ----------------

DEVI void gload16(const bf16* g, bf16* l) {
    __builtin_amdgcn_global_load_lds(
        (const __attribute__((address_space(1))) void*)g,
        (__attribute__((address_space(3))) void*)l, 16, 0, 0);
}

// C = A(MxK) @ BT(NxK)^T ; XCD-grouped block swizzle (requires (M/128)%8==0).
// EPI 0: qkv scatter (q scaled by 1/sqrt(32)*log2e); EPI 1: +bias; EPI 2: +bias,GELU
template <int EPI>
__global__ __launch_bounds__(256)
void k_gemm(const bf16* __restrict__ A, const bf16* __restrict__ BT,
            const float* __restrict__ bias, bf16* __restrict__ out,
            int M, int N, int K) {
    constexpr int BK = 64;
    __shared__ bf16 As[128 * BK];
    __shared__ bf16 Bs[128 * BK];

    const int nb = N >> 7;
    // swizzle: all bn-blocks of one bm land on the same XCD (bm == bid%8 mod 8)
    const int g = blockIdx.x;
    const int xcd = g & 7;
    const int ii = g >> 3;
    const int tt = ii / nb;
    const int bm = tt * 8 + xcd;
    const int bn = ii - tt * nb;

    const int tid = threadIdx.x;
    const int lane = tid & 63;
    const int wv = tid >> 6;
    const int wr = wv >> 1, wc = wv & 1;
    const int lg = lane >> 4, lc = lane & 15;

    const bf16* Ab = A + (size_t)bm * 128 * K;
    const bf16* Bb = BT + (size_t)bn * 128 * K;

    f32x4 acc[4][4];
#pragma unroll
    for (int mi = 0; mi < 4; mi++)
#pragma unroll
        for (int ni = 0; ni < 4; ni++) acc[mi][ni] = {0.f, 0.f, 0.f, 0.f};

    const int kiters = K / BK;
    const int srow = (lane >> 3);
    const int scol = (lane & 7) * 8;

    for (int kt = 0; kt < kiters; kt++) {
        const int k0 = kt * BK;
#pragma unroll
        for (int i = 0; i < 4; i++) {
            int ch = wv * 4 + i;
            int row = ch * 8 + srow;
            gload16(Ab + (size_t)row * K + k0 + scol, &As[ch * 512]);
            gload16(Bb + (size_t)row * K + k0 + scol, &Bs[ch * 512]);
        }
        // explicit drain of global_load_lds before the barrier (replay-race fix)
        asm volatile("s_waitcnt vmcnt(0)" ::: "memory");
        __syncthreads();
#pragma unroll
        for (int kk = 0; kk < 2; kk++) {
            s16x8 af[4], bfv[4];
#pragma unroll
            for (int mi = 0; mi < 4; mi++)
                af[mi] = *(const s16x8*)&As[(64 * wr + 16 * mi + lc) * BK + kk * 32 + 8 * lg];
#pragma unroll
            for (int ni = 0; ni < 4; ni++)
                bfv[ni] = *(const s16x8*)&Bs[(64 * wc + 16 * ni + lc) * BK + kk * 32 + 8 * lg];
#pragma unroll
            for (int mi = 0; mi < 4; mi++)
#pragma unroll
                for (int ni = 0; ni < 4; ni++)
                    acc[mi][ni] = __builtin_amdgcn_mfma_f32_16x16x32_bf16(
                        af[mi], bfv[ni], acc[mi][ni], 0, 0, 0);
        }
        __syncthreads();
    }

    const int rbase = bm * 128 + 64 * wr + 4 * lg;
    const int cbase = bn * 128 + 64 * wc + lc;
#pragma unroll
    for (int mi = 0; mi < 4; mi++) {
#pragma unroll
        for (int ni = 0; ni < 4; ni++) {
            const int gc = cbase + 16 * ni;
#pragma unroll
            for (int r2 = 0; r2 < 4; r2++) {
                const int gr = rbase + 16 * mi + r2;
                float val = acc[mi][ni][r2];
                if constexpr (EPI == 0) {
                    int which = gc / DIM;
                    int remc = gc - which * DIM;
                    int hh = remc >> 5, dh = remc & 31;
                    if (which == 0) val *= 0.25503527f; // (1/sqrt(32))*log2(e)
                    int wn = gr / WP;
                    int p = gr - wn * WP;
                    out[(size_t)which * TOKDIM +
                        ((size_t)(wn * HEADS + hh) * WP + p) * DH + dh] = __float2bfloat16(val);
                } else if constexpr (EPI == 1) {
                    val += bias[gc];
                    out[(size_t)gr * N + gc] = __float2bfloat16(val);
                } else {
                    val += bias[gc];
                    val = 0.5f * val * (1.0f + erff(val * 0.70710678118654752f));
                    out[(size_t)gr * N + gc] = __float2bfloat16(val);
                }
            }
        }
    }
}

// ---------------- fused window attention ----------------
// block = one (window, head); 3 waves x 192 threads; wave s owns strips {3s,3s+1,3s+2}
// (16 rows each). Q per-strip global->reg; K,V^T staged once; Ps per-wave (reused
// across strips, no inter-wave barrier after staging). Strides padded to 168.
// Softmax in exp2 domain, no max-subtract, normalize O after PV.
__global__ __launch_bounds__(192)
void k_attn(const bf16* __restrict__ q, const bf16* __restrict__ kmat,
            const bf16* __restrict__ v, const bf16* __restrict__ tab,
            bf16* __restrict__ out) {
    __shared__ bf16 Ks[WP * DH];        // [144][32] 9216 B
    __shared__ bf16 VTs[DH * 168];      // [32][168] 10752 B, cols 144..167 zero
    __shared__ bf16 Ps[3][16][168];     // per-wave [16][168] 16128 B, cols 144..159 zero
    __shared__ unsigned char regn[WP];

    const int bid = blockIdx.x;
    const int wn = bid / HEADS, head = bid - wn * HEADS;
    const int mz = wn / (MH * MW);
    const int rem = wn - mz * (MH * MW);
    const int mh = rem / MW, mw = rem - (rem / MW) * MW;
    const int tile = (mz * MH + mh) * HEADS + head;   // wt*12 + head

    const int tid = threadIdx.x;
    const int lane = tid & 63;
    const int s = tid >> 6;              // wave 0..2
    const int lg = lane >> 4, lc = lane & 15;

    const size_t base = (size_t)(wn * HEADS + head) * (WP * DH);
    // stage K row-major, V transposed [32][168]
    {
        short* vt = (short*)VTs;
#pragma unroll
        for (int e2 = 0; e2 < 3; e2++) {
            int idx = tid + 192 * e2;    // 0..575
            *(s16x8*)(Ks + idx * 8) = *(const s16x8*)(kmat + base + idx * 8);
            s16x8 vv = *(const s16x8*)(v + base + idx * 8);
            int p = idx >> 2;
            int d0 = (idx & 3) * 8;
#pragma unroll
            for (int e = 0; e < 8; e++) vt[(d0 + e) * 168 + p] = vv[e];
        }
        // zero VT cols 144..167 (192 threads x one s16x4 covers 32x24)
        { int d = tid / 6, rm = tid - d * 6;
          *(s16x4*)(vt + d * 168 + 144 + rm * 4) = (s16x4){0, 0, 0, 0}; }
        // zero this wave's Ps pad cols 144..159 (64 lanes x one s16x4 covers 16x16)
        { short* pz = (short*)&Ps[s][0][0];
          *(s16x4*)(pz + (lane >> 2) * 168 + 144 + (lane & 3) * 4) = (s16x4){0, 0, 0, 0}; }
        if (tid < WP) {
            int lz = tid / 72, rp = tid - lz * 72;
            int lh = rp / 12, lw = rp - lh * 12;
            int zr = (mz == 3) ? (lz + 1) : 0;
            int hr = (mh == 15) ? (lh < 3 ? 1 : 2) : 0;
            int wbit = (lw < 6) ? 1 : 2;
            regn[tid] = (unsigned char)((zr * 3 + hr) * 4 + wbit);
        }
    }
    __syncthreads();

    const f32x4 zf = {0.f, 0.f, 0.f, 0.f};
    const bf16* tb = tab + (size_t)tile * (WP * WP);
    bf16* ob = out + (size_t)wn * (WP * DIM) + head * DH;
    short* ps = (short*)&Ps[s][0][0];
    const bf16* psb = &Ps[s][0][0];

    for (int t = 0; t < 3; t++) {
        const int strip = 3 * s + t;
        const int ib = 16 * strip + 4 * lg;
        // Q fragment direct from global (wave covers a dense 1KB row-block)
        s16x8 aq = *(const s16x8*)(q + base + (size_t)(16 * strip + lc) * DH + 8 * lg);
        f32x4 sacc[9];
        // QK^T (q pre-scaled incl log2e)
#pragma unroll
        for (int jt = 0; jt < 9; jt++) {
            s16x8 bk = *(const s16x8*)(Ks + (16 * jt + lc) * DH + 8 * lg);
            sacc[jt] = __builtin_amdgcn_mfma_f32_16x16x32_bf16(aq, bk, zf, 0, 0, 0);
        }
        // + expanded bias (includes z/h mask), log2-scaled
#pragma unroll
        for (int jt = 0; jt < 9; jt++) {
            int j = 16 * jt + lc;
#pragma unroll
            for (int r2 = 0; r2 < 4; r2++)
                sacc[jt][r2] += __bfloat162float(tb[(ib + r2) * WP + j]);
        }
        // residual w-region mask (only boundary-mw windows)
        if (mw == 14) {
            int ri[4];
#pragma unroll
            for (int r2 = 0; r2 < 4; r2++) ri[r2] = regn[ib + r2];
#pragma unroll
            for (int jt = 0; jt < 9; jt++) {
                int rj = regn[16 * jt + lc];
#pragma unroll
                for (int r2 = 0; r2 < 4; r2++) {
                    bool m = ((ri[r2] >> 2) == (rj >> 2)) && ((ri[r2] & 3) != (rj & 3));
                    if (m) sacc[jt][r2] -= 144.2695f;
                }
            }
        }
        // exp2 (no max-subtract) + row sums
        float inv[4];
#pragma unroll
        for (int r2 = 0; r2 < 4; r2++) {
            float sum = 0.f;
#pragma unroll
            for (int jt = 0; jt < 9; jt++) {
                float pe = exp2f(sacc[jt][r2]);
                sacc[jt][r2] = pe;
                sum += pe;
            }
#pragma unroll
            for (int o = 1; o < 16; o <<= 1) sum += __shfl_xor(sum, o);
            inv[r2] = 1.0f / sum;
        }
        // store unnormalized P row-major [16][168] (wave-private; no barrier needed)
#pragma unroll
        for (int jt = 0; jt < 9; jt++)
#pragma unroll
            for (int r2 = 0; r2 < 4; r2++)
                ps[(4 * lg + r2) * 168 + 16 * jt + lc] = f2b(sacc[jt][r2]);
        // PV : O[16 x 32] (b128 fragment reads; compiler inserts lgkmcnt for RAW)
        f32x4 oacc[2] = {zf, zf};
#pragma unroll
        for (int c = 0; c < 5; c++) {
            s16x8 ap = *(const s16x8*)(psb + lc * 168 + 32 * c + 8 * lg);
#pragma unroll
            for (int nt = 0; nt < 2; nt++) {
                s16x8 bv = *(const s16x8*)(VTs + (16 * nt + lc) * 168 + 32 * c + 8 * lg);
                oacc[nt] = __builtin_amdgcn_mfma_f32_16x16x32_bf16(ap, bv, oacc[nt], 0, 0, 0);
            }
        }
#pragma unroll
        for (int nt = 0; nt < 2; nt++)
#pragma unroll
            for (int r2 = 0; r2 < 4; r2++)
                ob[(size_t)(ib + r2) * DIM + 16 * nt + lc] =
                    __float2bfloat16(oacc[nt][r2] * inv[r2]);
    }
}

// ---------------- LayerNorm kernels ----------------

__global__ __launch_bounds__(128)
void k_ln1(const bf16* __restrict__ y, const float* __restrict__ x,
           const float* __restrict__ w, const float* __restrict__ b,
           bf16* __restrict__ x1b, int r0) {
    __shared__ float red[4];
    const int rl = blockIdx.x, tid = threadIdx.x;
    const int t = row_to_token(r0 + rl);
    float v[3];
#pragma unroll
    for (int e = 0; e < 3; e++) v[e] = __bfloat162float(y[(size_t)rl * DIM + tid + 128 * e]);
    float s = v[0] + v[1] + v[2];
    float s2 = v[0] * v[0] + v[1] * v[1] + v[2] * v[2];
#pragma unroll
    for (int o = 1; o < 64; o <<= 1) { s += __shfl_xor(s, o); s2 += __shfl_xor(s2, o); }
    const int wv = tid >> 6;
    if ((tid & 63) == 0) { red[wv * 2] = s; red[wv * 2 + 1] = s2; }
    __syncthreads();
    s = red[0] + red[2]; s2 = red[1] + red[3];
    float mean = s * (1.f / 384.f);
    float var = fmaxf(s2 * (1.f / 384.f) - mean * mean, 0.f);
    float rs = rsqrtf(var + 1e-5f);
#pragma unroll
    for (int e = 0; e < 3; e++) {
        int c = tid + 128 * e;
        float o = (v[e] - mean) * rs * w[c] + b[c];
        float xo = x[(size_t)t * DIM + c] + o;
        ((short*)x1b)[(size_t)t * DIM + c] = f2b(xo);
    }
}

__global__ __launch_bounds__(128)
void k_ln2(const bf16* __restrict__ h, const bf16* __restrict__ x1b,
           const float* __restrict__ w, const float* __restrict__ b,
           float* __restrict__ out) {
    __shared__ float red[4];
    const int r = blockIdx.x, tid = threadIdx.x;
    float v[3];
#pragma unroll
    for (int e = 0; e < 3; e++) v[e] = __bfloat162float(h[(size_t)r * DIM + tid + 128 * e]);
    float s = v[0] + v[1] + v[2];
    float s2 = v[0] * v[0] + v[1] * v[1] + v[2] * v[2];
#pragma unroll
    for (int o = 1; o < 64; o <<= 1) { s += __shfl_xor(s, o); s2 += __shfl_xor(s2, o); }
    const int wv = tid >> 6;
    if ((tid & 63) == 0) { red[wv * 2] = s; red[wv * 2 + 1] = s2; }
    __syncthreads();
    s = red[0] + red[2]; s2 = red[1] + red[3];
    float mean = s * (1.f / 384.f);
    float var = fmaxf(s2 * (1.f / 384.f) - mean * mean, 0.f);
    float rs = rsqrtf(var + 1e-5f);
#pragma unroll
    for (int e = 0; e < 3; e++) {
        int c = tid + 128 * e;
        float o = (v[e] - mean) * rs * w[c] + b[c];
        out[(size_t)r * DIM + c] = __bfloat162float(x1b[(size_t)r * DIM + c]) + o;
    }
}

// ---------------- launcher ----------------
// Workspace map (bytes):
//  0         wqkvT(884736) wprojT(294912) w1T(1179648) w2T(1179648)
//  3538944   btr f32 (10174464)
//  13713408  tab bf16 (31850496)
//  45563904  D1: qkv (318504960) -> x1b(106168320) + ytmp/h1c(141557760 @D1+106168320)
//  364068864 D2: xw -> aout -> htmp (106168320)
//  peak 470237184

extern "C" void kernel_launch(void* const* d_in, const int* in_sizes, int n_in,
                              void* d_out, int out_size, void* d_ws, size_t ws_size,
                              hipStream_t stream) {
    const float* x      = (const float*)d_in[0];
    const float* w_qkv  = (const float*)d_in[1];
    const float* w_proj = (const float*)d_in[2];
    const float* b_proj = (const float*)d_in[3];
    const float* btab   = (const float*)d_in[4];
    const float* ln1w   = (const float*)d_in[5];
    const float* ln1b   = (const float*)d_in[6];
    const float* ln2w   = (const float*)d_in[7];
    const float* ln2b   = (const float*)d_in[8];
    const float* w1     = (const float*)d_in[9];
    const float* b1     = (const float*)d_in[10];
    const float* w2     = (const float*)d_in[11];
    const float* b2     = (const float*)d_in[12];

    const size_t NEED = 470237184ULL;
    if (ws_size < NEED) {
        k_fill<<<(out_size + 255) / 256, 256, 0, stream>>>((float*)d_out, out_size, 12345.0f);
        return;
    }

    char* ws = (char*)d_ws;
    bf16* wqkvT  = (bf16*)(ws + 0);
    bf16* wprojT = (bf16*)(ws + 884736);
    bf16* w1T    = (bf16*)(ws + 1179648);
    bf16* w2T    = (bf16*)(ws + 2359296);
    float* btr   = (float*)(ws + 3538944);
    bf16* tab    = (bf16*)(ws + 13713408);

    const size_t D1 = 45563904;
    const size_t D2 = 364068864;

    bf16* qkv  = (bf16*)(ws + D1);
    bf16* x1b  = (bf16*)(ws + D1);
    bf16* ytmp = (bf16*)(ws + D1 + 106168320);
    bf16* h1c  = (bf16*)(ws + D1 + 106168320);
    bf16* xw   = (bf16*)(ws + D2);
    bf16* aout = (bf16*)(ws + D2);
    bf16* htmp = (bf16*)(ws + D2);

    // prep
    k_wcast<<<(442368 + 255) / 256, 256, 0, stream>>>(w_qkv, wqkvT, 384, 1152);
    k_wcast<<<(147456 + 255) / 256, 256, 0, stream>>>(w_proj, wprojT, 384, 384);
    k_wcast<<<(589824 + 255) / 256, 256, 0, stream>>>(w1, w1T, 384, 1536);
    k_wcast<<<(589824 + 255) / 256, 256, 0, stream>>>(w2, w2T, 1536, 384);
    k_btr<<<(2543616 + 255) / 256, 256, 0, stream>>>(btab, btr);
    k_mktab<<<(768 * WP * WP + 255) / 256, 256, 0, stream>>>(btr, tab);
    k_gather_x<<<(TOK * 96 + 255) / 256, 256, 0, stream>>>(x, xw);

    // qkv = xw @ w_qkv (scatter epilogue)
    k_gemm<0><<<dim3((TOK / 128) * 9), 256, 0, stream>>>(xw, wqkvT, nullptr, qkv, TOK, 1152, 384);

    // attention (192 threads, 3 waves, 4 blocks/CU)
    k_attn<<<dim3(WN * HEADS), 192, 0, stream>>>(qkv, qkv + TOKDIM, qkv + 2 * TOKDIM, tab, aout);

    // proj + LN1 + residual (chunked; qkv region becomes x1b)
    for (int c = 0; c < NC; c++) {
        k_gemm<1><<<dim3((CM / 128) * 3), 256, 0, stream>>>(
            aout + (size_t)c * CM * DIM, wprojT, b_proj, ytmp, CM, 384, 384);
        k_ln1<<<dim3(CM), 128, 0, stream>>>(ytmp, x, ln1w, ln1b, x1b, c * CM);
    }

    // MLP (chunked)
    for (int c = 0; c < NC; c++) {
        k_gemm<2><<<dim3((CM / 128) * 12), 256, 0, stream>>>(
            x1b + (size_t)c * CM * DIM, w1T, b1, h1c, CM, 1536, 384);
        k_gemm<1><<<dim3((CM / 128) * 3), 256, 0, stream>>>(
            h1c, w2T, b2, htmp + (size_t)c * CM * DIM, CM, 384, 1536);
    }

    // final LN + residual -> d_out (fp32)
    k_ln2<<<dim3(TOK), 128, 0, stream>>>(htmp, x1b, ln2w, ln2b, (float*)d_out);
}

// Round 9
// 1427.913 us; speedup vs baseline: 1.2505x; 1.0088x over previous
//
#include <hip/hip_runtime.h>
#include <hip/hip_bf16.h>
#include <math.h>

typedef __hip_bfloat16 bf16;
typedef __attribute__((ext_vector_type(4))) float f32x4;
typedef __attribute__((ext_vector_type(16))) float f32x16;
typedef __attribute__((ext_vector_type(8))) short s16x8;
typedef __attribute__((ext_vector_type(4))) short s16x4;

#define DEVI __device__ __forceinline__

constexpr int ZD = 8, HD = 96, WD = 180;
constexpr int WZ = 2, WH = 6, WWn = 12;
constexpr int MZ = 4, MH = 16, MW = 15;
constexpr int WP = 144, WN = 960;
constexpr int DIM = 384, HEADS = 12, DH = 32;
constexpr int TOK = ZD * HD * WD;            // 138240
constexpr size_t TOKDIM = (size_t)TOK * DIM; // 53084160
constexpr int NC = 3, CM = TOK / NC;         // 46080 rows/chunk, mb=360 (div 8)

DEVI short f2b(float f) {
    bf16 h = __float2bfloat16(f);
    return *reinterpret_cast<short*>(&h);
}

DEVI int row_to_token(int r) {
    int wn = r / WP;
    int p  = r - wn * WP;
    int mz = wn / (MH * MW);
    int rem = wn - mz * (MH * MW);
    int mh = rem / MW;
    int mw = rem - mh * MW;
    int lz = p / (WH * WWn);
    int rp = p - lz * (WH * WWn);
    int lh = rp / WWn;
    int lw = rp - lh * WWn;
    int zp = mz * WZ + lz + 1;  if (zp >= ZD) zp -= ZD;
    int hp = mh * WH + lh + 3;  if (hp >= HD) hp -= HD;
    int wp = mw * WWn + lw + 6; if (wp >= WD) wp -= WD;
    return (zp * HD + hp) * WD + wp;
}

// ---------------- prep kernels ----------------

__global__ __launch_bounds__(256)
void k_fill(float* __restrict__ out, int n, float v) {
    int i = blockIdx.x * blockDim.x + threadIdx.x;
    if (i < n) out[i] = v;
}

__global__ __launch_bounds__(256)
void k_wcast(const float* __restrict__ w, bf16* __restrict__ wt, int K, int N) {
    int idx = blockIdx.x * blockDim.x + threadIdx.x;
    if (idx >= K * N) return;
    int n = idx / K;
    int k = idx - n * K;
    wt[idx] = __float2bfloat16(w[(size_t)k * N + n]);
}

// btr[(wt*12+h)*3312 + pos] = bt[pos*768 + wt*12 + h] * log2(e)
__global__ __launch_bounds__(256)
void k_btr(const float* __restrict__ bt, float* __restrict__ btr) {
    int idx = blockIdx.x * blockDim.x + threadIdx.x;
    if (idx >= 64 * 12 * 3312) return;
    int wth = idx / 3312;
    int pos = idx - wth * 3312;
    btr[idx] = bt[(size_t)pos * 768 + wth] * 1.4426950408889634f;
}

// expand bias + (z,h)-region mask -> tab[(wt*12+h)][i][j], bf16, log2-scaled
__global__ __launch_bounds__(256)
void k_mktab(const float* __restrict__ btr, bf16* __restrict__ tab) {
    int idx = blockIdx.x * blockDim.x + threadIdx.x;
    if (idx >= 768 * WP * WP) return;
    int t = idx / (WP * WP);
    int e = idx - t * (WP * WP);
    int i = e / WP, j = e - i * WP;
    int wt = t / 12;
    int mz = wt >> 4, mh = wt & 15;
    int lzi = i / 72, ri_ = i - lzi * 72, lhi = ri_ / 12, lwi = ri_ - lhi * 12;
    int lzj = j / 72, rj_ = j - lzj * 72, lhj = rj_ / 12, lwj = rj_ - lhj * 12;
    int cA = lzi * 828 + lhi * 23 + lwi;
    int cB = lzj * 1656 + lhj * 138 + (11 - lwj);
    float vv = btr[(size_t)t * 3312 + cA + cB];
    int zri = (mz == 3) ? (lzi + 1) : 0, zrj = (mz == 3) ? (lzj + 1) : 0;
    int hri = (mh == 15) ? (lhi < 3 ? 1 : 2) : 0, hrj = (mh == 15) ? (lhj < 3 ? 1 : 2) : 0;
    if (zri != zrj || hri != hrj) vv -= 144.26950408889634f; // -100*log2(e)
    tab[idx] = __float2bfloat16(vv);
}

__global__ __launch_bounds__(256)
void k_gather_x(const float* __restrict__ x, bf16* __restrict__ xw) {
    int idx = blockIdx.x * blockDim.x + threadIdx.x;
    if (idx >= TOK * 96) return;
    int r  = idx / 96;
    int c4 = (idx - r * 96) * 4;
    int t  = row_to_token(r);
    const float4 vv = *(const float4*)(x + (size_t)t * DIM + c4);
    s16x4 o;
    o[0] = f2b(vv.x); o[1] = f2b(vv.y); o[2] = f2b(vv.z); o[3] = f2b(vv.w);
    *(s16x4*)((short*)xw + (size_t)r * DIM + c4) = o;
}

// ---------------- GEMM ----------------

DEVI void gload16(const bf16* g, bf16* l) {
    __builtin_amdgcn_global_load_lds(
        (const __attribute__((address_space(1))) void*)g,
        (__attribute__((address_space(3))) void*)l, 16, 0, 0);
}

// C = A(MxK) @ BT(NxK)^T via 32x32x16 MFMA with SWAPPED operands (weights = A-op,
// activations = B-op) so D = C^T in registers: each reg-quad = 4 consecutive
// features of one token -> s16x4 stores. LDS tiles XOR-swizzled (T2) with
// pre-swizzled global source (global_load_lds dest stays linear).
// XCD-grouped block swizzle (requires (M/128)%8==0).
// EPI 0: qkv scatter (q scaled by 1/sqrt(32)*log2e); EPI 1: +bias; EPI 2: +bias,GELU
template <int EPI>
__global__ __launch_bounds__(256)
void k_gemm(const bf16* __restrict__ A, const bf16* __restrict__ BT,
            const float* __restrict__ bias, bf16* __restrict__ out,
            int M, int N, int K) {
    constexpr int BK = 64;
    __shared__ bf16 As[128 * BK];
    __shared__ bf16 Bs[128 * BK];

    const int nb = N >> 7;
    const int g = blockIdx.x;
    const int xcd = g & 7;
    const int ii = g >> 3;
    const int tt = ii / nb;
    const int bm = tt * 8 + xcd;
    const int bn = ii - tt * nb;

    const int tid = threadIdx.x;
    const int lane = tid & 63;
    const int wv = tid >> 6;
    const int wr = wv >> 1;          // feature-half of wave tile (N-dim)
    const int wc = wv & 1;           // token-half (M-dim)
    const int l31 = lane & 31, hi = lane >> 5;

    const bf16* Ab = A + (size_t)bm * 128 * K;
    const bf16* Bb = BT + (size_t)bn * 128 * K;

    f32x16 acc[2][2] = {{{}, {}}, {{}, {}}};

    const int kiters = K / BK;
    const int srow = lane >> 3;                         // 0..7 within 8-row chunk
    const int scol = ((lane & 7) ^ srow) * 8;           // pre-swizzled k-offset (bf16)

    // per-lane read constants (row, row&7) for the 4 fragment rows
    // a-operand rows (features, from Bs): 64*wr + 32*ni + l31
    // b-operand rows (tokens,  from As): 64*wc + 32*mi + l31
    int ra[2], rb[2], rax[2], rbx[2];
#pragma unroll
    for (int i2 = 0; i2 < 2; i2++) {
        ra[i2] = 64 * wr + 32 * i2 + l31; rax[i2] = ra[i2] & 7;
        rb[i2] = 64 * wc + 32 * i2 + l31; rbx[i2] = rb[i2] & 7;
    }

    for (int kt = 0; kt < kiters; kt++) {
        const int k0 = kt * BK;
#pragma unroll
        for (int i = 0; i < 4; i++) {
            int ch = wv * 4 + i;
            int row = ch * 8 + srow;
            gload16(Ab + (size_t)row * K + k0 + scol, &As[ch * 512]);
            gload16(Bb + (size_t)row * K + k0 + scol, &Bs[ch * 512]);
        }
        // explicit drain of global_load_lds before the barrier (replay-race fix)
        asm volatile("s_waitcnt vmcnt(0)" ::: "memory");
        __syncthreads();
#pragma unroll
        for (int kk = 0; kk < 4; kk++) {
            const int s0 = 2 * kk + hi;                 // 16B-slot index 0..7
            s16x8 af[2], bfv[2];
#pragma unroll
            for (int ni = 0; ni < 2; ni++)
                af[ni] = *(const s16x8*)&Bs[ra[ni] * BK + ((s0 ^ rax[ni]) * 8)];
#pragma unroll
            for (int mi = 0; mi < 2; mi++)
                bfv[mi] = *(const s16x8*)&As[rb[mi] * BK + ((s0 ^ rbx[mi]) * 8)];
#pragma unroll
            for (int ni = 0; ni < 2; ni++)
#pragma unroll
                for (int mi = 0; mi < 2; mi++)
                    acc[ni][mi] = __builtin_amdgcn_mfma_f32_32x32x16_bf16(
                        af[ni], bfv[mi], acc[ni][mi], 0, 0, 0);
        }
        __syncthreads();
    }

    // epilogue: D[row=feature][col=token]; reg 4*rq+r2 -> feature (8*rq+4*hi+r2)
    const int tokbase = bm * 128 + 64 * wc + l31;
    const int featbase = bn * 128 + 64 * wr + 4 * hi;
#pragma unroll
    for (int ni = 0; ni < 2; ni++) {
#pragma unroll
        for (int mi = 0; mi < 2; mi++) {
            const int tok = tokbase + 32 * mi;
#pragma unroll
            for (int rq = 0; rq < 4; rq++) {
                const int f0 = featbase + 32 * ni + 8 * rq;
                float v0 = acc[ni][mi][4 * rq + 0];
                float v1 = acc[ni][mi][4 * rq + 1];
                float v2 = acc[ni][mi][4 * rq + 2];
                float v3 = acc[ni][mi][4 * rq + 3];
                if constexpr (EPI == 0) {
                    const int which = f0 / DIM;
                    const int rem = f0 - which * DIM;
                    const int head = rem >> 5, dh = rem & 31;
                    if (which == 0) {
                        v0 *= 0.25503527f; v1 *= 0.25503527f; // (1/sqrt(32))*log2(e)
                        v2 *= 0.25503527f; v3 *= 0.25503527f;
                    }
                    const int wn = tok / WP, p = tok - wn * WP;
                    s16x4 o; o[0] = f2b(v0); o[1] = f2b(v1); o[2] = f2b(v2); o[3] = f2b(v3);
                    *(s16x4*)(out + (size_t)which * TOKDIM +
                              ((size_t)(wn * HEADS + head) * WP + p) * DH + dh) = o;
                } else if constexpr (EPI == 1) {
                    const float4 bv = *(const float4*)(bias + f0);
                    s16x4 o;
                    o[0] = f2b(v0 + bv.x); o[1] = f2b(v1 + bv.y);
                    o[2] = f2b(v2 + bv.z); o[3] = f2b(v3 + bv.w);
                    *(s16x4*)(out + (size_t)tok * N + f0) = o;
                } else {
                    const float4 bv = *(const float4*)(bias + f0);
                    float g0 = v0 + bv.x, g1 = v1 + bv.y, g2 = v2 + bv.z, g3 = v3 + bv.w;
                    g0 = 0.5f * g0 * (1.0f + erff(g0 * 0.70710678118654752f));
                    g1 = 0.5f * g1 * (1.0f + erff(g1 * 0.70710678118654752f));
                    g2 = 0.5f * g2 * (1.0f + erff(g2 * 0.70710678118654752f));
                    g3 = 0.5f * g3 * (1.0f + erff(g3 * 0.70710678118654752f));
                    s16x4 o; o[0] = f2b(g0); o[1] = f2b(g1); o[2] = f2b(g2); o[3] = f2b(g3);
                    *(s16x4*)(out + (size_t)tok * N + f0) = o;
                }
            }
        }
    }
}

// ---------------- fused window attention ----------------
// block = one (window, head); 3 waves x 192 threads; wave s owns strips {3s,3s+1,3s+2}
// (16 rows each). Q per-strip global->reg; K,V^T staged once; Ps per-wave (reused
// across strips, no inter-wave barrier after staging). Strides padded to 168.
// Softmax in exp2 domain, no max-subtract, normalize O after PV.
__global__ __launch_bounds__(192)
void k_attn(const bf16* __restrict__ q, const bf16* __restrict__ kmat,
            const bf16* __restrict__ v, const bf16* __restrict__ tab,
            bf16* __restrict__ out) {
    __shared__ bf16 Ks[WP * DH];        // [144][32] 9216 B
    __shared__ bf16 VTs[DH * 168];      // [32][168] 10752 B, cols 144..167 zero
    __shared__ bf16 Ps[3][16][168];     // per-wave [16][168] 16128 B, cols 144..159 zero
    __shared__ unsigned char regn[WP];

    const int bid = blockIdx.x;
    const int wn = bid / HEADS, head = bid - wn * HEADS;
    const int mz = wn / (MH * MW);
    const int rem = wn - mz * (MH * MW);
    const int mh = rem / MW, mw = rem - (rem / MW) * MW;
    const int tile = (mz * MH + mh) * HEADS + head;   // wt*12 + head

    const int tid = threadIdx.x;
    const int lane = tid & 63;
    const int s = tid >> 6;              // wave 0..2
    const int lg = lane >> 4, lc = lane & 15;

    const size_t base = (size_t)(wn * HEADS + head) * (WP * DH);
    // stage K row-major, V transposed [32][168]
    {
        short* vt = (short*)VTs;
#pragma unroll
        for (int e2 = 0; e2 < 3; e2++) {
            int idx = tid + 192 * e2;    // 0..575
            *(s16x8*)(Ks + idx * 8) = *(const s16x8*)(kmat + base + idx * 8);
            s16x8 vv = *(const s16x8*)(v + base + idx * 8);
            int p = idx >> 2;
            int d0 = (idx & 3) * 8;
#pragma unroll
            for (int e = 0; e < 8; e++) vt[(d0 + e) * 168 + p] = vv[e];
        }
        // zero VT cols 144..167 (192 threads x one s16x4 covers 32x24)
        { int d = tid / 6, rm = tid - d * 6;
          *(s16x4*)(vt + d * 168 + 144 + rm * 4) = (s16x4){0, 0, 0, 0}; }
        // zero this wave's Ps pad cols 144..159 (64 lanes x one s16x4 covers 16x16)
        { short* pz = (short*)&Ps[s][0][0];
          *(s16x4*)(pz + (lane >> 2) * 168 + 144 + (lane & 3) * 4) = (s16x4){0, 0, 0, 0}; }
        if (tid < WP) {
            int lz = tid / 72, rp = tid - lz * 72;
            int lh = rp / 12, lw = rp - lh * 12;
            int zr = (mz == 3) ? (lz + 1) : 0;
            int hr = (mh == 15) ? (lh < 3 ? 1 : 2) : 0;
            int wbit = (lw < 6) ? 1 : 2;
            regn[tid] = (unsigned char)((zr * 3 + hr) * 4 + wbit);
        }
    }
    __syncthreads();

    const f32x4 zf = {0.f, 0.f, 0.f, 0.f};
    const bf16* tb = tab + (size_t)tile * (WP * WP);
    bf16* ob = out + (size_t)wn * (WP * DIM) + head * DH;
    short* ps = (short*)&Ps[s][0][0];
    const bf16* psb = &Ps[s][0][0];

    for (int t = 0; t < 3; t++) {
        const int strip = 3 * s + t;
        const int ib = 16 * strip + 4 * lg;
        // Q fragment direct from global (wave covers a dense 1KB row-block)
        s16x8 aq = *(const s16x8*)(q + base + (size_t)(16 * strip + lc) * DH + 8 * lg);
        f32x4 sacc[9];
        // QK^T (q pre-scaled incl log2e)
#pragma unroll
        for (int jt = 0; jt < 9; jt++) {
            s16x8 bk = *(const s16x8*)(Ks + (16 * jt + lc) * DH + 8 * lg);
            sacc[jt] = __builtin_amdgcn_mfma_f32_16x16x32_bf16(aq, bk, zf, 0, 0, 0);
        }
        // + expanded bias (includes z/h mask), log2-scaled
#pragma unroll
        for (int jt = 0; jt < 9; jt++) {
            int j = 16 * jt + lc;
#pragma unroll
            for (int r2 = 0; r2 < 4; r2++)
                sacc[jt][r2] += __bfloat162float(tb[(ib + r2) * WP + j]);
        }
        // residual w-region mask (only boundary-mw windows)
        if (mw == 14) {
            int ri[4];
#pragma unroll
            for (int r2 = 0; r2 < 4; r2++) ri[r2] = regn[ib + r2];
#pragma unroll
            for (int jt = 0; jt < 9; jt++) {
                int rj = regn[16 * jt + lc];
#pragma unroll
                for (int r2 = 0; r2 < 4; r2++) {
                    bool m = ((ri[r2] >> 2) == (rj >> 2)) && ((ri[r2] & 3) != (rj & 3));
                    if (m) sacc[jt][r2] -= 144.2695f;
                }
            }
        }
        // exp2 (no max-subtract) + row sums
        float inv[4];
#pragma unroll
        for (int r2 = 0; r2 < 4; r2++) {
            float sum = 0.f;
#pragma unroll
            for (int jt = 0; jt < 9; jt++) {
                float pe = exp2f(sacc[jt][r2]);
                sacc[jt][r2] = pe;
                sum += pe;
            }
#pragma unroll
            for (int o = 1; o < 16; o <<= 1) sum += __shfl_xor(sum, o);
            inv[r2] = 1.0f / sum;
        }
        // store unnormalized P row-major [16][168] (wave-private; no barrier needed)
#pragma unroll
        for (int jt = 0; jt < 9; jt++)
#pragma unroll
            for (int r2 = 0; r2 < 4; r2++)
                ps[(4 * lg + r2) * 168 + 16 * jt + lc] = f2b(sacc[jt][r2]);
        // PV : O[16 x 32] (b128 fragment reads; compiler inserts lgkmcnt for RAW)
        f32x4 oacc[2] = {zf, zf};
#pragma unroll
        for (int c = 0; c < 5; c++) {
            s16x8 ap = *(const s16x8*)(psb + lc * 168 + 32 * c + 8 * lg);
#pragma unroll
            for (int nt = 0; nt < 2; nt++) {
                s16x8 bv = *(const s16x8*)(VTs + (16 * nt + lc) * 168 + 32 * c + 8 * lg);
                oacc[nt] = __builtin_amdgcn_mfma_f32_16x16x32_bf16(ap, bv, oacc[nt], 0, 0, 0);
            }
        }
#pragma unroll
        for (int nt = 0; nt < 2; nt++)
#pragma unroll
            for (int r2 = 0; r2 < 4; r2++)
                ob[(size_t)(ib + r2) * DIM + 16 * nt + lc] =
                    __float2bfloat16(oacc[nt][r2] * inv[r2]);
    }
}

// ---------------- LayerNorm kernels ----------------

__global__ __launch_bounds__(128)
void k_ln1(const bf16* __restrict__ y, const float* __restrict__ x,
           const float* __restrict__ w, const float* __restrict__ b,
           bf16* __restrict__ x1b, int r0) {
    __shared__ float red[4];
    const int rl = blockIdx.x, tid = threadIdx.x;
    const int t = row_to_token(r0 + rl);
    float v[3];
#pragma unroll
    for (int e = 0; e < 3; e++) v[e] = __bfloat162float(y[(size_t)rl * DIM + tid + 128 * e]);
    float s = v[0] + v[1] + v[2];
    float s2 = v[0] * v[0] + v[1] * v[1] + v[2] * v[2];
#pragma unroll
    for (int o = 1; o < 64; o <<= 1) { s += __shfl_xor(s, o); s2 += __shfl_xor(s2, o); }
    const int wv = tid >> 6;
    if ((tid & 63) == 0) { red[wv * 2] = s; red[wv * 2 + 1] = s2; }
    __syncthreads();
    s = red[0] + red[2]; s2 = red[1] + red[3];
    float mean = s * (1.f / 384.f);
    float var = fmaxf(s2 * (1.f / 384.f) - mean * mean, 0.f);
    float rs = rsqrtf(var + 1e-5f);
#pragma unroll
    for (int e = 0; e < 3; e++) {
        int c = tid + 128 * e;
        float o = (v[e] - mean) * rs * w[c] + b[c];
        float xo = x[(size_t)t * DIM + c] + o;
        ((short*)x1b)[(size_t)t * DIM + c] = f2b(xo);
    }
}

__global__ __launch_bounds__(128)
void k_ln2(const bf16* __restrict__ h, const bf16* __restrict__ x1b,
           const float* __restrict__ w, const float* __restrict__ b,
           float* __restrict__ out) {
    __shared__ float red[4];
    const int r = blockIdx.x, tid = threadIdx.x;
    float v[3];
#pragma unroll
    for (int e = 0; e < 3; e++) v[e] = __bfloat162float(h[(size_t)r * DIM + tid + 128 * e]);
    float s = v[0] + v[1] + v[2];
    float s2 = v[0] * v[0] + v[1] * v[1] + v[2] * v[2];
#pragma unroll
    for (int o = 1; o < 64; o <<= 1) { s += __shfl_xor(s, o); s2 += __shfl_xor(s2, o); }
    const int wv = tid >> 6;
    if ((tid & 63) == 0) { red[wv * 2] = s; red[wv * 2 + 1] = s2; }
    __syncthreads();
    s = red[0] + red[2]; s2 = red[1] + red[3];
    float mean = s * (1.f / 384.f);
    float var = fmaxf(s2 * (1.f / 384.f) - mean * mean, 0.f);
    float rs = rsqrtf(var + 1e-5f);
#pragma unroll
    for (int e = 0; e < 3; e++) {
        int c = tid + 128 * e;
        float o = (v[e] - mean) * rs * w[c] + b[c];
        out[(size_t)r * DIM + c] = __bfloat162float(x1b[(size_t)r * DIM + c]) + o;
    }
}

// ---------------- launcher ----------------
// Workspace map (bytes):
//  0         wqkvT(884736) wprojT(294912) w1T(1179648) w2T(1179648)
//  3538944   btr f32 (10174464)
//  13713408  tab bf16 (31850496)
//  45563904  D1: qkv (318504960) -> x1b(106168320) + ytmp/h1c(141557760 @D1+106168320)
//  364068864 D2: xw -> aout -> htmp (106168320)
//  peak 470237184

extern "C" void kernel_launch(void* const* d_in, const int* in_sizes, int n_in,
                              void* d_out, int out_size, void* d_ws, size_t ws_size,
                              hipStream_t stream) {
    const float* x      = (const float*)d_in[0];
    const float* w_qkv  = (const float*)d_in[1];
    const float* w_proj = (const float*)d_in[2];
    const float* b_proj = (const float*)d_in[3];
    const float* btab   = (const float*)d_in[4];
    const float* ln1w   = (const float*)d_in[5];
    const float* ln1b   = (const float*)d_in[6];
    const float* ln2w   = (const float*)d_in[7];
    const float* ln2b   = (const float*)d_in[8];
    const float* w1     = (const float*)d_in[9];
    const float* b1     = (const float*)d_in[10];
    const float* w2     = (const float*)d_in[11];
    const float* b2     = (const float*)d_in[12];

    const size_t NEED = 470237184ULL;
    if (ws_size < NEED) {
        k_fill<<<(out_size + 255) / 256, 256, 0, stream>>>((float*)d_out, out_size, 12345.0f);
        return;
    }

    char* ws = (char*)d_ws;
    bf16* wqkvT  = (bf16*)(ws + 0);
    bf16* wprojT = (bf16*)(ws + 884736);
    bf16* w1T    = (bf16*)(ws + 1179648);
    bf16* w2T    = (bf16*)(ws + 2359296);
    float* btr   = (float*)(ws + 3538944);
    bf16* tab    = (bf16*)(ws + 13713408);

    const size_t D1 = 45563904;
    const size_t D2 = 364068864;

    bf16* qkv  = (bf16*)(ws + D1);
    bf16* x1b  = (bf16*)(ws + D1);
    bf16* ytmp = (bf16*)(ws + D1 + 106168320);
    bf16* h1c  = (bf16*)(ws + D1 + 106168320);
    bf16* xw   = (bf16*)(ws + D2);
    bf16* aout = (bf16*)(ws + D2);
    bf16* htmp = (bf16*)(ws + D2);

    // prep
    k_wcast<<<(442368 + 255) / 256, 256, 0, stream>>>(w_qkv, wqkvT, 384, 1152);
    k_wcast<<<(147456 + 255) / 256, 256, 0, stream>>>(w_proj, wprojT, 384, 384);
    k_wcast<<<(589824 + 255) / 256, 256, 0, stream>>>(w1, w1T, 384, 1536);
    k_wcast<<<(589824 + 255) / 256, 256, 0, stream>>>(w2, w2T, 1536, 384);
    k_btr<<<(2543616 + 255) / 256, 256, 0, stream>>>(btab, btr);
    k_mktab<<<(768 * WP * WP + 255) / 256, 256, 0, stream>>>(btr, tab);
    k_gather_x<<<(TOK * 96 + 255) / 256, 256, 0, stream>>>(x, xw);

    // qkv = xw @ w_qkv (scatter epilogue)
    k_gemm<0><<<dim3((TOK / 128) * 9), 256, 0, stream>>>(xw, wqkvT, nullptr, qkv, TOK, 1152, 384);

    // attention (192 threads, 3 waves, 4 blocks/CU)
    k_attn<<<dim3(WN * HEADS), 192, 0, stream>>>(qkv, qkv + TOKDIM, qkv + 2 * TOKDIM, tab, aout);

    // proj + LN1 + residual (chunked; qkv region becomes x1b)
    for (int c = 0; c < NC; c++) {
        k_gemm<1><<<dim3((CM / 128) * 3), 256, 0, stream>>>(
            aout + (size_t)c * CM * DIM, wprojT, b_proj, ytmp, CM, 384, 384);
        k_ln1<<<dim3(CM), 128, 0, stream>>>(ytmp, x, ln1w, ln1b, x1b, c * CM);
    }

    // MLP (chunked)
    for (int c = 0; c < NC; c++) {
        k_gemm<2><<<dim3((CM / 128) * 12), 256, 0, stream>>>(
            x1b + (size_t)c * CM * DIM, w1T, b1, h1c, CM, 1536, 384);
        k_gemm<1><<<dim3((CM / 128) * 3), 256, 0, stream>>>(
            h1c, w2T, b2, htmp + (size_t)c * CM * DIM, CM, 384, 1536);
    }

    // final LN + residual -> d_out (fp32)
    k_ln2<<<dim3(TOK), 128, 0, stream>>>(htmp, x1b, ln2w, ln2b, (float*)d_out);
}